// Round 3
// baseline (638.973 us; speedup 1.0000x reference)
//
#include <hip/hip_runtime.h>
#include <cstdint>

typedef unsigned long long u64;

#define BATCH   32
#define H       1024
#define W       1024
#define WPR     16                 // 64-bit words per row (1024/64)
#define TR      16                 // interior rows per tile
#define HALO    8                  // = generations
#define BR      (TR + 2*HALO)      // 32 buffer rows
#define BRP     (BR + 2)           // +2 zero-pad rows
#define WP      (WPR + 2)          // +2 zero-pad word-cols
#define THREADS 256
#define NWAVES  (THREADS/64)       // 4
#define GENS    8
#define GRID    (BATCH * (H / TR)) // 2048 blocks -> 8/CU, 32 waves/CU
#define NTOT    33554432ULL        // B*H*W

__device__ __forceinline__ u64 shflxor64(u64 v, int m) {
    return (u64)__shfl_xor((long long)v, m, 64);
}

// Fused: pack fp32->bits, 8 Life generations in LDS (overlapped halo tiling),
// unpack with ALIGNED float4 stores (shifted-quad scheme to absorb the +1
// scalar offset of d_out), integer reductions, last-block writes scalars.
__global__ __launch_bounds__(THREADS)
void gol_fused(const float* __restrict__ in_state,
               const float* __restrict__ target,
               float* __restrict__ out,
               unsigned int* __restrict__ counters)
{
    __shared__ u64 buf[2][BRP][WP];   // 2*34*18*8 = 9792 B
    __shared__ int isLast;

    const int tile = blockIdx.x;             // 0..2047
    const int tpb  = H / TR;                 // 64 tiles per batch
    const int b    = tile / tpb;
    const int r0   = (tile - b * tpb) * TR;  // first interior global row

    const int tid  = threadIdx.x;
    const int wave = tid >> 6;
    const int lane = tid & 63;

    // Zero both buffers (pads must stay zero through all steps).
    for (int i = tid; i < 2 * BRP * WP; i += THREADS)
        ((u64*)buf)[i] = 0ULL;
    __syncthreads();

    const size_t boff = (size_t)b * H * W;
    const float* inb  = in_state + boff;

    // ---- pack: buffer row br (0..BR-1) <- global row r0-HALO+br ----
    const int sub   = lane & 15;
    const int wsub  = lane >> 4;
    for (int br = wave; br < BR; br += NWAVES) {
        int gr = r0 - HALO + br;
        if (gr < 0 || gr >= H) continue;    // wave-uniform
        const float4* rowp4 = (const float4*)(inb + (size_t)gr * W);
        #pragma unroll
        for (int g = 0; g < 4; ++g) {
            float4 f = rowp4[g * 64 + lane];
            u64 nib = (u64)((f.x > 0.5f) | ((f.y > 0.5f) << 1) |
                            ((f.z > 0.5f) << 2) | ((f.w > 0.5f) << 3));
            u64 v = nib << (sub * 4);
            v |= shflxor64(v, 1);
            v |= shflxor64(v, 2);
            v |= shflxor64(v, 4);
            v |= shflxor64(v, 8);
            if (sub == 0)
                buf[0][br + 1][g * 4 + wsub + 1] = v;
        }
    }
    __syncthreads();

    // ---- 8 generations, bit-parallel full adders ----
    int cur = 0;
    for (int step = 0; step < GENS; ++step) {
        #pragma unroll
        for (int k = 0; k < (BR * WPR) / THREADS; ++k) {   // 2 iters
            int idx = tid + k * THREADS;
            int br = idx >> 4;
            int c  = (idx & 15) + 1;
            int r  = br + 1;
            int gr = r0 - HALO + br;

            u64 uL = buf[cur][r-1][c-1], uC = buf[cur][r-1][c], uR = buf[cur][r-1][c+1];
            u64 mL = buf[cur][r  ][c-1], mC = buf[cur][r  ][c], mR = buf[cur][r  ][c+1];
            u64 dL = buf[cur][r+1][c-1], dC = buf[cur][r+1][c], dR = buf[cur][r+1][c+1];

            u64 uw = (uC << 1) | (uL >> 63), ue = (uC >> 1) | (uR << 63);
            u64 mw = (mC << 1) | (mL >> 63), me = (mC >> 1) | (mR << 63);
            u64 dw = (dC << 1) | (dL >> 63), de = (dC >> 1) | (dR << 63);
            u64 o0 = uw ^ uC ^ ue, t0 = (uw & uC) | (ue & (uw ^ uC));
            u64 o1 = mw ^ mC ^ me, t1 = (mw & mC) | (me & (mw ^ mC));
            u64 o2 = dw ^ dC ^ de, t2 = (dw & dC) | (de & (dw ^ dC));

            u64 oa = o0 ^ o1 ^ o2;
            u64 oc = (o0 & o1) | (o2 & (o0 ^ o1));
            u64 ts = t0 ^ t1 ^ t2;
            u64 tc = (t0 & t1) | (t2 & (t0 ^ t1));
            u64 b1 = oc ^ ts;
            u64 cc = oc & ts;
            u64 b2 = cc ^ tc;
            u64 b3 = cc & tc;
            u64 eq3 = oa & b1 & ~(b2 | b3);          // sum9 == 3
            u64 eq4 = (~oa) & (~b1) & b2 & (~b3);    // sum9 == 4
            u64 nxtw = eq3 | (mC & eq4);

            buf[cur ^ 1][r][c] = (gr >= 0 && gr < H) ? nxtw : 0ULL;
        }
        __syncthreads();
        cur ^= 1;
    }

    // ---- epilogue: shifted quads so every out-store is 16B-aligned ----
    // out layout: out[0]=loss, out[1..]=state, out[1+NTOT..]=target copy.
    // Quad k (k=0..254) of a row covers row elements 4k+3..4k+6; out index
    // rowbase + 1 + 4k+3 === 0 mod 4. One lane/row handles head(3)+tail(1).
    float* o_state = out + 1;
    float* o_tgt   = out + 1 + NTOT;

    unsigned int mism = 0, live = 0;
    for (int lr = wave; lr < TR; lr += NWAVES) {
        int br = HALO + lr;
        int gr = r0 + lr;
        size_t rowbase = boff + (size_t)gr * W;
        const u64* wrow = &buf[cur][br + 1][1];   // wrow[0..15] data, wrow[16]=0 pad
        const float* trow = target + rowbase;
        float* osrow = o_state + rowbase;
        float* otrow = o_tgt + rowbase;
        #pragma unroll
        for (int g = 0; g < 4; ++g) {
            int k = g * 64 + lane;
            if (k < 255) {
                int bitbase = 4 * k + 3;
                int w0 = bitbase >> 6;
                int sh = bitbase & 63;            // in {3,7,...,63}, never 0
                u64 lo = wrow[w0];
                u64 hi = wrow[w0 + 1];
                unsigned bits = (unsigned)(((lo >> sh) | (hi << (64 - sh))) & 0xFULL);
                float4 t = *(const float4*)(trow + bitbase);
                unsigned tb = (unsigned)((t.x > 0.5f) | ((t.y > 0.5f) << 1) |
                                         ((t.z > 0.5f) << 2) | ((t.w > 0.5f) << 3));
                mism += (unsigned)__popc(bits ^ tb);
                live += (unsigned)__popc(bits);
                float4 sv;
                sv.x = (float)(bits & 1u);
                sv.y = (float)((bits >> 1) & 1u);
                sv.z = (float)((bits >> 2) & 1u);
                sv.w = (float)((bits >> 3) & 1u);
                *(float4*)(osrow + bitbase) = sv;   // aligned
                *(float4*)(otrow + bitbase) = t;    // aligned
            } else {
                // head elements 0,1,2 and tail element 1023
                u64 wfirst = wrow[0];
                u64 wlast  = wrow[15];
                unsigned hb  = (unsigned)(wfirst & 7ULL);
                unsigned tbit = (unsigned)(wlast >> 63);
                float t0 = trow[0], t1 = trow[1], t2 = trow[2], t3 = trow[1023];
                unsigned htb = (unsigned)((t0 > 0.5f) | ((t1 > 0.5f) << 1) | ((t2 > 0.5f) << 2));
                unsigned ttb = (unsigned)(t3 > 0.5f);
                mism += (unsigned)__popc(hb ^ htb) + (tbit ^ ttb);
                live += (unsigned)__popc(hb) + tbit;
                osrow[0] = (float)(hb & 1u);
                osrow[1] = (float)((hb >> 1) & 1u);
                osrow[2] = (float)((hb >> 2) & 1u);
                osrow[1023] = (float)tbit;
                otrow[0] = t0; otrow[1] = t1; otrow[2] = t2; otrow[1023] = t3;
            }
        }
    }

    // per-wave reduction: pack both counters (wave sums <= 4096 < 2^16)
    unsigned int comb = (mism << 16) | live;
    #pragma unroll
    for (int m = 1; m < 64; m <<= 1)
        comb += (unsigned int)__shfl_xor((int)comb, m, 64);
    if (lane == 0) {
        atomicAdd(&counters[0], comb >> 16);
        atomicAdd(&counters[1], comb & 0xFFFFu);
    }

    // ---- last block writes the scalars ----
    if (tid == 0) {
        __threadfence();
        unsigned prev = atomicAdd(&counters[2], 1u);
        isLast = (prev == GRID - 1) ? 1 : 0;
    }
    __syncthreads();
    if (isLast && tid == 0) {
        unsigned int mm = atomicAdd(&counters[0], 0u);   // coherent read
        unsigned int lv = atomicAdd(&counters[1], 0u);
        out[0]            = (float)((double)mm / (double)NTOT);
        out[1 + 2*NTOT]   = (float)lv;
        out[2 + 2*NTOT]   = (mm > 0) ? 1.0f : 0.0f;
    }
}

extern "C" void kernel_launch(void* const* d_in, const int* in_sizes, int n_in,
                              void* d_out, int out_size, void* d_ws, size_t ws_size,
                              hipStream_t stream) {
    (void)in_sizes; (void)n_in; (void)out_size; (void)ws_size;
    const float* in_state = (const float*)d_in[0];
    const float* target   = (const float*)d_in[1];
    float* out = (float*)d_out;
    unsigned int* counters = (unsigned int*)d_ws;

    hipMemsetAsync(d_ws, 0, 3 * sizeof(unsigned int), stream);

    gol_fused<<<dim3(GRID), dim3(THREADS), 0, stream>>>(in_state, target, out, counters);
}

// Round 4
// 462.877 us; speedup vs baseline: 1.3804x; 1.3804x over previous
//
#include <hip/hip_runtime.h>
#include <cstdint>

typedef unsigned long long u64;

#define BATCH   32
#define H       1024
#define W       1024
#define WPR     16                 // 64-bit words per row (1024/64)
#define TR      64                 // interior rows per tile
#define HALO    8                  // = generations
#define BR      (TR + 2*HALO)      // 80 buffer rows
#define BRP     (BR + 2)           // +2 zero-pad rows
#define WP      (WPR + 2)          // +2 zero-pad word-cols
#define THREADS 512
#define NWAVES  (THREADS/64)       // 8
#define GENS    8
#define GRID    (BATCH * (H / TR)) // 512 blocks
#define NTOT    33554432ULL        // B*H*W

__device__ __forceinline__ u64 shflxor64(u64 v, int m) {
    return (u64)__shfl_xor((long long)v, m, 64);
}

// Fused: pack fp32->bits (float4 + shfl assemble), 8 Life generations in LDS
// (overlapped halo tiling, exact for interior rows), unpack with ALIGNED
// float4 stores (shifted-quad scheme absorbs d_out's +1 scalar offset).
// Reductions: wave shfl -> LDS -> ONE u64 atomic per block (atomic-tail fix).
__global__ __launch_bounds__(THREADS)
void gol_fused(const float* __restrict__ in_state,
               const float* __restrict__ target,
               float* __restrict__ out,
               u64* __restrict__ counters)
{
    __shared__ u64 buf[2][BRP][WP];   // 2*82*18*8 = 23616 B
    __shared__ unsigned int wsum[NWAVES];

    const int tile = blockIdx.x;             // 0..511
    const int tpb  = H / TR;                 // 16 tiles per batch
    const int b    = tile / tpb;
    const int r0   = (tile - b * tpb) * TR;  // first interior global row

    const int tid  = threadIdx.x;
    const int wave = tid >> 6;
    const int lane = tid & 63;

    // Zero both buffers (pads must stay zero through all steps).
    for (int i = tid; i < 2 * BRP * WP; i += THREADS)
        ((u64*)buf)[i] = 0ULL;
    __syncthreads();

    const size_t boff = (size_t)b * H * W;
    const float* inb  = in_state + boff;

    // ---- pack: buffer row br (0..BR-1) <- global row r0-HALO+br ----
    const int sub   = lane & 15;
    const int wsub  = lane >> 4;
    for (int br = wave; br < BR; br += NWAVES) {
        int gr = r0 - HALO + br;
        if (gr < 0 || gr >= H) continue;    // wave-uniform
        const float4* rowp4 = (const float4*)(inb + (size_t)gr * W);
        #pragma unroll
        for (int g = 0; g < 4; ++g) {
            float4 f = rowp4[g * 64 + lane];
            u64 nib = (u64)((f.x > 0.5f) | ((f.y > 0.5f) << 1) |
                            ((f.z > 0.5f) << 2) | ((f.w > 0.5f) << 3));
            u64 v = nib << (sub * 4);
            v |= shflxor64(v, 1);
            v |= shflxor64(v, 2);
            v |= shflxor64(v, 4);
            v |= shflxor64(v, 8);
            if (sub == 0)
                buf[0][br + 1][g * 4 + wsub + 1] = v;
        }
    }
    __syncthreads();

    // ---- 8 generations, bit-parallel full adders ----
    int cur = 0;
    for (int step = 0; step < GENS; ++step) {
        for (int idx = tid; idx < BR * WPR; idx += THREADS) {
            int br = idx >> 4;
            int c  = (idx & 15) + 1;
            int r  = br + 1;
            int gr = r0 - HALO + br;

            u64 uL = buf[cur][r-1][c-1], uC = buf[cur][r-1][c], uR = buf[cur][r-1][c+1];
            u64 mL = buf[cur][r  ][c-1], mC = buf[cur][r  ][c], mR = buf[cur][r  ][c+1];
            u64 dL = buf[cur][r+1][c-1], dC = buf[cur][r+1][c], dR = buf[cur][r+1][c+1];

            u64 uw = (uC << 1) | (uL >> 63), ue = (uC >> 1) | (uR << 63);
            u64 mw = (mC << 1) | (mL >> 63), me = (mC >> 1) | (mR << 63);
            u64 dw = (dC << 1) | (dL >> 63), de = (dC >> 1) | (dR << 63);
            u64 o0 = uw ^ uC ^ ue, t0 = (uw & uC) | (ue & (uw ^ uC));
            u64 o1 = mw ^ mC ^ me, t1 = (mw & mC) | (me & (mw ^ mC));
            u64 o2 = dw ^ dC ^ de, t2 = (dw & dC) | (de & (dw ^ dC));

            u64 oa = o0 ^ o1 ^ o2;
            u64 oc = (o0 & o1) | (o2 & (o0 ^ o1));
            u64 ts = t0 ^ t1 ^ t2;
            u64 tc = (t0 & t1) | (t2 & (t0 ^ t1));
            u64 b1 = oc ^ ts;
            u64 cc = oc & ts;
            u64 b2 = cc ^ tc;
            u64 b3 = cc & tc;
            u64 eq3 = oa & b1 & ~(b2 | b3);          // sum9 == 3
            u64 eq4 = (~oa) & (~b1) & b2 & (~b3);    // sum9 == 4
            u64 nxtw = eq3 | (mC & eq4);

            buf[cur ^ 1][r][c] = (gr >= 0 && gr < H) ? nxtw : 0ULL;
        }
        __syncthreads();
        cur ^= 1;
    }

    // ---- epilogue: shifted quads so every out-store is 16B-aligned ----
    // out layout: out[0]=loss, out[1..]=state, out[1+NTOT..]=target copy.
    // Quad k (k=0..254) of a row covers row elements 4k+3..4k+6; out index
    // rowbase + 1 + 4k+3 === 0 mod 4. One lane/row handles head(3)+tail(1).
    float* o_state = out + 1;
    float* o_tgt   = out + 1 + NTOT;

    unsigned int mism = 0, live = 0;
    for (int lr = wave; lr < TR; lr += NWAVES) {
        int br = HALO + lr;
        int gr = r0 + lr;
        size_t rowbase = boff + (size_t)gr * W;
        const u64* wrow = &buf[cur][br + 1][1];   // wrow[0..15] data, wrow[16]=0 pad
        const float* trow = target + rowbase;
        float* osrow = o_state + rowbase;
        float* otrow = o_tgt + rowbase;
        #pragma unroll
        for (int g = 0; g < 4; ++g) {
            int k = g * 64 + lane;
            if (k < 255) {
                int bitbase = 4 * k + 3;
                int w0 = bitbase >> 6;
                int sh = bitbase & 63;            // in {3,7,...,63}, never 0
                u64 lo = wrow[w0];
                u64 hi = wrow[w0 + 1];
                unsigned bits = (unsigned)(((lo >> sh) | (hi << (64 - sh))) & 0xFULL);
                float4 t = *(const float4*)(trow + bitbase);
                unsigned tb = (unsigned)((t.x > 0.5f) | ((t.y > 0.5f) << 1) |
                                         ((t.z > 0.5f) << 2) | ((t.w > 0.5f) << 3));
                mism += (unsigned)__popc(bits ^ tb);
                live += (unsigned)__popc(bits);
                float4 sv;
                sv.x = (float)(bits & 1u);
                sv.y = (float)((bits >> 1) & 1u);
                sv.z = (float)((bits >> 2) & 1u);
                sv.w = (float)((bits >> 3) & 1u);
                *(float4*)(osrow + bitbase) = sv;   // aligned
                *(float4*)(otrow + bitbase) = t;    // aligned
            } else {
                // head elements 0,1,2 and tail element 1023
                u64 wfirst = wrow[0];
                u64 wlast  = wrow[15];
                unsigned hb  = (unsigned)(wfirst & 7ULL);
                unsigned tbit = (unsigned)(wlast >> 63);
                float t0 = trow[0], t1 = trow[1], t2 = trow[2], t3 = trow[1023];
                unsigned htb = (unsigned)((t0 > 0.5f) | ((t1 > 0.5f) << 1) | ((t2 > 0.5f) << 2));
                unsigned ttb = (unsigned)(t3 > 0.5f);
                mism += (unsigned)__popc(hb ^ htb) + (tbit ^ ttb);
                live += (unsigned)__popc(hb) + tbit;
                osrow[0] = (float)(hb & 1u);
                osrow[1] = (float)((hb >> 1) & 1u);
                osrow[2] = (float)((hb >> 2) & 1u);
                osrow[1023] = (float)tbit;
                otrow[0] = t0; otrow[1] = t1; otrow[2] = t2; otrow[1023] = t3;
            }
        }
    }

    // wave reduction (per-wave sums <= 8192 each, fits 16-bit packed)
    unsigned int comb = (mism << 16) | live;
    #pragma unroll
    for (int m = 1; m < 64; m <<= 1)
        comb += (unsigned int)__shfl_xor((int)comb, m, 64);
    if (lane == 0) wsum[wave] = comb;
    __syncthreads();

    // block reduction -> ONE u64 atomic per block
    if (tid == 0) {
        unsigned int bm = 0, bl = 0;
        #pragma unroll
        for (int i = 0; i < NWAVES; ++i) {
            bm += wsum[i] >> 16;
            bl += wsum[i] & 0xFFFFu;
        }
        atomicAdd(counters, ((u64)bm << 32) | (u64)bl);
    }
}

__global__ void gol_finalize(const u64* __restrict__ counters,
                             float* __restrict__ out)
{
    u64 c = *counters;
    unsigned int mism = (unsigned int)(c >> 32);
    unsigned int live = (unsigned int)(c & 0xFFFFFFFFULL);
    out[0]            = (float)((double)mism / (double)NTOT);
    out[1 + 2*NTOT]   = (float)live;
    out[2 + 2*NTOT]   = (mism > 0) ? 1.0f : 0.0f;
}

extern "C" void kernel_launch(void* const* d_in, const int* in_sizes, int n_in,
                              void* d_out, int out_size, void* d_ws, size_t ws_size,
                              hipStream_t stream) {
    (void)in_sizes; (void)n_in; (void)out_size; (void)ws_size;
    const float* in_state = (const float*)d_in[0];
    const float* target   = (const float*)d_in[1];
    float* out = (float*)d_out;
    u64* counters = (u64*)d_ws;

    hipMemsetAsync(d_ws, 0, sizeof(u64), stream);

    gol_fused<<<dim3(GRID), dim3(THREADS), 0, stream>>>(in_state, target, out, counters);
    gol_finalize<<<1, 1, 0, stream>>>(counters, out);
}